// Round 3
// baseline (464.152 us; speedup 1.0000x reference)
//
#include <hip/hip_runtime.h>
#include <math.h>

// Problem constants (fixed by the reference).
#define BB 32          // batch
#define MM 8192        // tokens
#define DD 256         // d_model
#define SCALE 0.0625f  // 1/sqrt(256)
#define WPB 64         // waves per batch  -> 128 tokens per wave
#define TPW (MM / WPB) // tokens per wave = 128
#define BLK_PER_B (WPB / 4)  // 4 waves per 256-thread block -> 16 blocks/batch
// Grid = 16*32 = 512 blocks = 2 blocks/CU (vgpr-safe for any <=256).
// BW-bound: per-CU VALU ~9K cyc, shuffle chain ~13K cyc vs ~96K cyc of HBM
// service time for this CU's 1.05 MB share of tokens.

using f4 = __attribute__((ext_vector_type(4))) float;

// ---------------------------------------------------------------------------
// Kernel 1, blocks 0..BB-1: r[b,e] = SCALE * ((query[b] @ q_w^T + q_b) @ k_w)[e]
// k_b dropped: softmax-invariant.
// Blocks BB..BB+7: transpose v_w into vwt (coalesced combine matmul) and
// (block BB) zero the per-batch combine semaphores.  Runs on otherwise-idle
// CUs -> free.  Stream order makes sem=0 visible to k_flash.
// ---------------------------------------------------------------------------
__global__ __launch_bounds__(256) void k_qr(
    const float* __restrict__ query, const float* __restrict__ q_w,
    const float* __restrict__ q_b, const float* __restrict__ k_w,
    const float* __restrict__ v_w, float* __restrict__ vwt,
    unsigned int* __restrict__ sem, float* __restrict__ r)
{
    const int tid = threadIdx.x;
    if (blockIdx.x >= BB) {
        const int t  = blockIdx.x - BB;   // 0..7
        if (t == 0 && tid < BB) sem[tid] = 0u;
        // --- v_w transpose: slab of 32 rows (d) -> columns of vwt.
        const int dj = tid & 31;          // d within slab
        const int e8 = tid >> 5;          // 0..7
        const int d  = t * 32 + dj;
        #pragma unroll 4
        for (int it = 0; it < 32; ++it) {
            const int e = it * 8 + e8;
            vwt[e * DD + d] = v_w[d * DD + e];
        }
        return;
    }

    const int b = blockIdx.x;
    __shared__ __align__(16) float qv[DD];
    __shared__ float qp[DD];
    qv[tid] = query[b * DD + tid];
    __syncthreads();
    // qp[d] = query[b] . q_w[d,:] + q_b[d]   (thread tid == d, f4 row-dot)
    float acc = q_b[tid];
    const f4* qw4 = (const f4*)(q_w + (size_t)tid * DD);
    const f4* qv4 = (const f4*)qv;
    #pragma unroll 8
    for (int e = 0; e < DD / 4; ++e) {
        const f4 a = qv4[e], w = qw4[e];
        acc += a.x * w.x + a.y * w.y + a.z * w.z + a.w * w.w;
    }
    qp[tid] = acc;
    __syncthreads();
    // r[e] = sum_d qp[d] * k_w[d,e]          (thread tid == e, coalesced)
    float racc = 0.f;
    #pragma unroll 8
    for (int d = 0; d < DD; ++d) racc += qp[d] * k_w[d * DD + tid];
    r[b * DD + tid] = racc * SCALE;
}

// ---------------------------------------------------------------------------
// Kernel 2 (fused): flash-style pass over tokens + decoupled per-batch
// combine.  Flash part unchanged from v3 (16-lane token groups, depth-2
// register prefetch).  After writing partials, each block does a
// device-scope release fence + atomicAdd on its batch's semaphore; the
// 16th (last) arriver acquires and performs the combine for that batch:
//   out[b,d] = sum_e (u[b,e]/l) * vwt[e,d] + v_b[d]
// No spinning -> no co-residency assumption, no deadlock risk.  Per-batch
// combines overlap with other batches' still-running flash blocks, and the
// third kernel launch + full-device drain disappear.
// ---------------------------------------------------------------------------
__global__ __launch_bounds__(256, 2) void k_flash(
    const float* __restrict__ tokens, const float* __restrict__ r,
    float* __restrict__ part_m, float* __restrict__ part_l,
    f4* __restrict__ part_u, unsigned int* __restrict__ sem,
    const float* __restrict__ vwt, const float* __restrict__ v_b,
    float* __restrict__ out)
{
    const int b    = blockIdx.y;
    const int blk  = blockIdx.x;          // 0..BLK_PER_B-1
    const int tid  = threadIdx.x;
    const int w    = tid >> 6;
    const int lane = tid & 63;
    const int g    = lane & 15;           // element-group position
    const int tg   = lane >> 4;           // token within 4-token subtile
    const int wi   = blk * 4 + w;         // wave index within batch, 0..WPB-1
    const int m0   = wi * TPW;

    // rr[c] matches the lane's element slice: elements [4g + 64c, +4)
    const f4* r4 = (const f4*)(r + b * DD);
    f4 rr[4];
    #pragma unroll
    for (int c = 0; c < 4; ++c) rr[c] = r4[16 * c + g];

    // f4 index of this lane's c=0 chunk of its token in subtile 0.
    const f4* tok = (const f4*)tokens + ((size_t)b * MM + m0) * (DD / 4)
                  + (size_t)tg * (DD / 4) + g;

    float mw = -INFINITY, lw = 0.f;
    f4 u[4] = {{0,0,0,0},{0,0,0,0},{0,0,0,0},{0,0,0,0}};

    auto body = [&](const f4* x) {
        // Partial dot over this lane's 16 elements (4 independent sub-dots).
        float s0 = x[0].x*rr[0].x + x[0].y*rr[0].y + x[0].z*rr[0].z + x[0].w*rr[0].w;
        float s1 = x[1].x*rr[1].x + x[1].y*rr[1].y + x[1].z*rr[1].z + x[1].w*rr[1].w;
        float s2 = x[2].x*rr[2].x + x[2].y*rr[2].y + x[2].z*rr[2].z + x[2].w*rr[2].w;
        float s3 = x[3].x*rr[3].x + x[3].y*rr[3].y + x[3].z*rr[3].z + x[3].w*rr[3].w;
        float p  = (s0 + s1) + (s2 + s3);

        // Reduce within the 16-lane group (broadcasts the logit to all 16).
        p += __shfl_xor(p, 1);
        p += __shfl_xor(p, 2);
        p += __shfl_xor(p, 4);
        p += __shfl_xor(p, 8);

        // Branchless online softmax (state uniform within the group).
        const float newm  = fmaxf(mw, p);
        const float alpha = __expf(mw - newm);   // exp(-inf)=0 on first iter
        const float wj    = __expf(p  - newm);
        mw = newm;
        lw = lw * alpha + wj;
        #pragma unroll
        for (int c = 0; c < 4; ++c) {
            u[c].x = u[c].x * alpha + wj * x[c].x;
            u[c].y = u[c].y * alpha + wj * x[c].y;
            u[c].z = u[c].z * alpha + wj * x[c].z;
            u[c].w = u[c].w * alpha + wj * x[c].w;
        }
    };

    const int NIT = TPW / 4;   // 32 iterations of 4 tokens
    // Software pipeline, depth 2: xa holds subtile it, xb holds it+1.
    f4 xa[4], xb[4];
    #pragma unroll
    for (int c = 0; c < 4; ++c)
        xa[c] = __builtin_nontemporal_load(tok + 16 * c);
    {
        const f4* t1 = tok + 4 * (DD / 4);
        #pragma unroll
        for (int c = 0; c < 4; ++c)
            xb[c] = __builtin_nontemporal_load(t1 + 16 * c);
    }

    for (int it = 0; it < NIT; it += 2) {
        f4 x[4];
        #pragma unroll
        for (int c = 0; c < 4; ++c) x[c] = xa[c];
        if (it + 2 < NIT) {
            const f4* nxt = tok + (size_t)(it + 2) * 4 * (DD / 4);
            #pragma unroll
            for (int c = 0; c < 4; ++c)
                xa[c] = __builtin_nontemporal_load(nxt + 16 * c);
        }
        body(x);

        #pragma unroll
        for (int c = 0; c < 4; ++c) x[c] = xb[c];
        if (it + 3 < NIT) {
            const f4* nxt = tok + (size_t)(it + 3) * 4 * (DD / 4);
            #pragma unroll
            for (int c = 0; c < 4; ++c)
                xb[c] = __builtin_nontemporal_load(nxt + 16 * c);
        }
        body(x);
    }

    // Merge the 4 group-states across the wave (offsets 16, 32).
    float gm = mw;
    gm = fmaxf(gm, __shfl_xor(gm, 16));
    gm = fmaxf(gm, __shfl_xor(gm, 32));
    const float beta = __expf(mw - gm);
    float L = lw * beta;
    L += __shfl_xor(L, 16);
    L += __shfl_xor(L, 32);
    #pragma unroll
    for (int c = 0; c < 4; ++c) {
        u[c].x *= beta; u[c].y *= beta; u[c].z *= beta; u[c].w *= beta;
        u[c].x += __shfl_xor(u[c].x, 16);
        u[c].y += __shfl_xor(u[c].y, 16);
        u[c].z += __shfl_xor(u[c].z, 16);
        u[c].w += __shfl_xor(u[c].w, 16);
        u[c].x += __shfl_xor(u[c].x, 32);
        u[c].y += __shfl_xor(u[c].y, 32);
        u[c].z += __shfl_xor(u[c].z, 32);
        u[c].w += __shfl_xor(u[c].w, 32);
    }

    const int pi = b * WPB + wi;
    if (lane == 0) { part_m[pi] = gm; part_l[pi] = L; }
    // f4 slot j holds elements [4j, 4j+4): slot = 16c + g, so lane `lane`
    // writes u[lane>>4] to slot `lane` (branchless select avoids scratch).
    f4 val = u[0];
    val = (tg == 1) ? u[1] : val;
    val = (tg == 2) ? u[2] : val;
    val = (tg == 3) ? u[3] : val;
    part_u[(size_t)pi * 64 + lane] = val;

    // ---- decoupled last-block-done combine for this batch ----
    __shared__ unsigned int s_old;
    __threadfence();                         // release our partials
    __syncthreads();                         // all waves' stores issued+fenced
    if (tid == 0) s_old = atomicAdd(&sem[b], 1u);
    __syncthreads();
    if (s_old != BLK_PER_B - 1) return;      // not the last arriver
    __threadfence();                         // acquire other blocks' partials

    __shared__ float sf[WPB];
    __shared__ float s_invl;
    __shared__ f4 suh[4][64];
    __shared__ __align__(16) float su[DD];

    // m/l reductions on wave 0 only: 64 lanes == WPB partials.
    if (tid < 64) {
        const float pm = part_m[b * WPB + tid];
        float gmax = pm;
        gmax = fmaxf(gmax, __shfl_xor(gmax, 32));
        gmax = fmaxf(gmax, __shfl_xor(gmax, 16));
        gmax = fmaxf(gmax, __shfl_xor(gmax, 8));
        gmax = fmaxf(gmax, __shfl_xor(gmax, 4));
        gmax = fmaxf(gmax, __shfl_xor(gmax, 2));
        gmax = fmaxf(gmax, __shfl_xor(gmax, 1));
        const float f = __expf(pm - gmax);
        sf[tid] = f;
        float lt = part_l[b * WPB + tid] * f;
        lt += __shfl_xor(lt, 32);
        lt += __shfl_xor(lt, 16);
        lt += __shfl_xor(lt, 8);
        lt += __shfl_xor(lt, 4);
        lt += __shfl_xor(lt, 2);
        lt += __shfl_xor(lt, 1);
        if (tid == 0) s_invl = 1.f / lt;
    }
    __syncthreads();

    // u[e] = sum_i part_u[b,i,e] * sf[i]  -- f4 slot per thread, 4 row-groups.
    const int slot = tid & 63;      // f4 slot = elements [4*slot, 4*slot+4)
    const int rg   = tid >> 6;      // row-group: rows rg, rg+4, rg+8, ...
    const f4* pu = part_u + (size_t)b * WPB * 64;
    f4 acc = {0.f, 0.f, 0.f, 0.f};
    #pragma unroll 8
    for (int i = rg; i < WPB; i += 4)
        acc += pu[(size_t)i * 64 + slot] * sf[i];
    suh[rg][slot] = acc;
    __syncthreads();
    if (tid < 64) {
        f4 s = suh[0][tid] + suh[1][tid] + suh[2][tid] + suh[3][tid];
        s *= s_invl;
        ((f4*)su)[tid] = s;
    }
    __syncthreads();

    // out[b,d] = su . vwt[:,d] + v_b[d]   (thread tid == d, coalesced on vwt)
    float o = v_b[tid];
    #pragma unroll 8
    for (int e = 0; e < DD; ++e) o += su[e] * vwt[e * DD + tid];
    out[b * DD + tid] = o;
}

extern "C" void kernel_launch(void* const* d_in, const int* in_sizes, int n_in,
                              void* d_out, int out_size, void* d_ws, size_t ws_size,
                              hipStream_t stream) {
    const float* query  = (const float*)d_in[0];
    const float* tokens = (const float*)d_in[1];
    const float* q_w    = (const float*)d_in[2];
    const float* q_b    = (const float*)d_in[3];
    const float* k_w    = (const float*)d_in[4];
    // d_in[5] = k_b: softmax-invariant, unused.
    const float* v_w    = (const float*)d_in[6];
    const float* v_b    = (const float*)d_in[7];
    float* out = (float*)d_out;

    // Workspace layout (floats): r[32*256] | part_m[32*64] | part_l[32*64]
    //                            | part_u[32*64*256] | vwt[256*256] | sem[32]
    float* ws     = (float*)d_ws;
    float* r      = ws;
    float* part_m = r + BB * DD;
    float* part_l = part_m + BB * WPB;
    float* part_u = part_l + BB * WPB;      // 48 KiB offset -> float4 aligned
    float* vwt    = part_u + (size_t)BB * WPB * DD;  // 16B-aligned
    unsigned int* sem = (unsigned int*)(vwt + DD * DD);

    k_qr<<<dim3(BB + 8), dim3(256), 0, stream>>>(query, q_w, q_b, k_w,
                                                 v_w, vwt, sem, r);
    k_flash<<<dim3(BLK_PER_B, BB), dim3(256), 0, stream>>>(
        tokens, r, part_m, part_l, (f4*)part_u, sem, vwt, v_b, out);
}

// Round 4
// 373.592 us; speedup vs baseline: 1.2424x; 1.2424x over previous
//
#include <hip/hip_runtime.h>
#include <math.h>

// Problem constants (fixed by the reference).
#define BB 32          // batch
#define MM 8192        // tokens
#define DD 256         // d_model
#define SCALE 0.0625f  // 1/sqrt(256)
#define WPB 64         // waves per batch  -> 128 tokens per wave
#define TPW (MM / WPB) // tokens per wave = 128
#define BLK_PER_B (WPB / 4)  // 4 waves per 256-thread block -> 16 blocks/batch
// Grid = 16*32 = 512 blocks = 2 blocks/CU (vgpr-safe for any <=256).
// NOTE (R3 lesson): do NOT fuse the combine via per-block agent-scope
// fences -- __threadfence() per producer block emits L2 writeback/inv and
// cost +76 us.  Three kernels it is.

using f4 = __attribute__((ext_vector_type(4))) float;

// ---------------------------------------------------------------------------
// Kernel 1, blocks 0..BB-1: r[b,e] = SCALE * ((query[b] @ q_w^T + q_b) @ k_w)[e]
// k_b dropped: softmax-invariant.
// Blocks BB..BB+7: transpose v_w into vwt (coalesced combine matmul),
// LDS-staged so the global reads are fully-coalesced f4 (one latency round)
// instead of scattered 32B runs.  Runs on otherwise-idle CUs -> free.
// These blocks are latency-bound (1 wave/SIMD), hence the deep unrolls.
// ---------------------------------------------------------------------------
__global__ __launch_bounds__(256) void k_qr(
    const float* __restrict__ query, const float* __restrict__ q_w,
    const float* __restrict__ q_b, const float* __restrict__ k_w,
    const float* __restrict__ v_w, float* __restrict__ vwt,
    float* __restrict__ r)
{
    const int tid = threadIdx.x;
    if (blockIdx.x >= BB) {
        // --- v_w transpose, slab of 32 d-rows, via LDS.
        __shared__ float tile[32][257];   // +1 pad: 2-way max on reads (free)
        const int t  = blockIdx.x - BB;   // 0..7
        const int d0 = t * 32;
        // Coalesced f4 read of the slab: 2048 f4 / 256 threads = 8 each,
        // all independent -> one exposed latency round.
        const f4* src = (const f4*)(v_w + (size_t)d0 * DD);
        #pragma unroll
        for (int k = 0; k < 8; ++k) {
            const int idx = k * 256 + tid;        // f4 index in slab
            const int row = idx >> 6, c4 = idx & 63;
            const f4 v = src[idx];
            tile[row][c4 * 4 + 0] = v.x;
            tile[row][c4 * 4 + 1] = v.y;
            tile[row][c4 * 4 + 2] = v.z;
            tile[row][c4 * 4 + 3] = v.w;
        }
        __syncthreads();
        // Write columns: 8 e-rows x 128B segments per instruction;
        // stores are fire-and-forget.
        const int dj = tid & 31, e8 = tid >> 5;
        #pragma unroll 8
        for (int it = 0; it < 32; ++it) {
            const int e = it * 8 + e8;
            vwt[e * DD + d0 + dj] = tile[dj][e];
        }
        return;
    }

    const int b = blockIdx.x;
    __shared__ __align__(16) float qv[DD];
    __shared__ float qp[DD];
    qv[tid] = query[b * DD + tid];
    __syncthreads();
    // qp[d] = query[b] . q_w[d,:] + q_b[d]   (thread tid == d, f4 row-dot)
    float acc = q_b[tid];
    const f4* qw4 = (const f4*)(q_w + (size_t)tid * DD);
    const f4* qv4 = (const f4*)qv;
    #pragma unroll 16
    for (int e = 0; e < DD / 4; ++e) {
        const f4 a = qv4[e], w = qw4[e];
        acc += a.x * w.x + a.y * w.y + a.z * w.z + a.w * w.w;
    }
    qp[tid] = acc;
    __syncthreads();
    // r[e] = sum_d qp[d] * k_w[d,e]          (thread tid == e, coalesced).
    // unroll 32: 32 outstanding loads -> 8 exposed latency rounds not 32.
    float racc = 0.f;
    #pragma unroll 32
    for (int d = 0; d < DD; ++d) racc += qp[d] * k_w[d * DD + tid];
    r[b * DD + tid] = racc * SCALE;
}

// ---------------------------------------------------------------------------
// Kernel 2: flash-style single pass over tokens, 16-lane token groups.
// Lane l owns elements {4*(l&15) + 64c + i | c=0..3, i=0..3} of token
// m0 + 4*it + (l>>4).  One iteration = 4 tokens = 4 coalesced dwordx4 loads.
// Logit reduction needs only shuffle offsets 1/2/4/8 (within 16-lane
// groups); the 4 group-states merge once at the end (offsets 16/32).
// Depth-2 register prefetch.  BW-bound: 268 MB / ~6.7 TB/s = ~40 us floor.
// ---------------------------------------------------------------------------
__global__ __launch_bounds__(256, 2) void k_flash(
    const float* __restrict__ tokens, const float* __restrict__ r,
    float* __restrict__ part_m, float* __restrict__ part_l,
    f4* __restrict__ part_u)
{
    const int b    = blockIdx.y;
    const int blk  = blockIdx.x;          // 0..BLK_PER_B-1
    const int tid  = threadIdx.x;
    const int w    = tid >> 6;
    const int lane = tid & 63;
    const int g    = lane & 15;           // element-group position
    const int tg   = lane >> 4;           // token within 4-token subtile
    const int wi   = blk * 4 + w;         // wave index within batch, 0..WPB-1
    const int m0   = wi * TPW;

    // rr[c] matches the lane's element slice: elements [4g + 64c, +4)
    const f4* r4 = (const f4*)(r + b * DD);
    f4 rr[4];
    #pragma unroll
    for (int c = 0; c < 4; ++c) rr[c] = r4[16 * c + g];

    // f4 index of this lane's c=0 chunk of its token in subtile 0.
    const f4* tok = (const f4*)tokens + ((size_t)b * MM + m0) * (DD / 4)
                  + (size_t)tg * (DD / 4) + g;

    float mw = -INFINITY, lw = 0.f;
    f4 u[4] = {{0,0,0,0},{0,0,0,0},{0,0,0,0},{0,0,0,0}};

    auto body = [&](const f4* x) {
        // Partial dot over this lane's 16 elements (4 independent sub-dots).
        float s0 = x[0].x*rr[0].x + x[0].y*rr[0].y + x[0].z*rr[0].z + x[0].w*rr[0].w;
        float s1 = x[1].x*rr[1].x + x[1].y*rr[1].y + x[1].z*rr[1].z + x[1].w*rr[1].w;
        float s2 = x[2].x*rr[2].x + x[2].y*rr[2].y + x[2].z*rr[2].z + x[2].w*rr[2].w;
        float s3 = x[3].x*rr[3].x + x[3].y*rr[3].y + x[3].z*rr[3].z + x[3].w*rr[3].w;
        float p  = (s0 + s1) + (s2 + s3);

        // Reduce within the 16-lane group (broadcasts the logit to all 16).
        p += __shfl_xor(p, 1);
        p += __shfl_xor(p, 2);
        p += __shfl_xor(p, 4);
        p += __shfl_xor(p, 8);

        // Branchless online softmax (state uniform within the group).
        const float newm  = fmaxf(mw, p);
        const float alpha = __expf(mw - newm);   // exp(-inf)=0 on first iter
        const float wj    = __expf(p  - newm);
        mw = newm;
        lw = lw * alpha + wj;
        #pragma unroll
        for (int c = 0; c < 4; ++c) {
            u[c].x = u[c].x * alpha + wj * x[c].x;
            u[c].y = u[c].y * alpha + wj * x[c].y;
            u[c].z = u[c].z * alpha + wj * x[c].z;
            u[c].w = u[c].w * alpha + wj * x[c].w;
        }
    };

    const int NIT = TPW / 4;   // 32 iterations of 4 tokens
    // Software pipeline, depth 2: xa holds subtile it, xb holds it+1.
    f4 xa[4], xb[4];
    #pragma unroll
    for (int c = 0; c < 4; ++c)
        xa[c] = __builtin_nontemporal_load(tok + 16 * c);
    {
        const f4* t1 = tok + 4 * (DD / 4);
        #pragma unroll
        for (int c = 0; c < 4; ++c)
            xb[c] = __builtin_nontemporal_load(t1 + 16 * c);
    }

    for (int it = 0; it < NIT; it += 2) {
        f4 x[4];
        #pragma unroll
        for (int c = 0; c < 4; ++c) x[c] = xa[c];
        if (it + 2 < NIT) {
            const f4* nxt = tok + (size_t)(it + 2) * 4 * (DD / 4);
            #pragma unroll
            for (int c = 0; c < 4; ++c)
                xa[c] = __builtin_nontemporal_load(nxt + 16 * c);
        }
        body(x);

        #pragma unroll
        for (int c = 0; c < 4; ++c) x[c] = xb[c];
        if (it + 3 < NIT) {
            const f4* nxt = tok + (size_t)(it + 3) * 4 * (DD / 4);
            #pragma unroll
            for (int c = 0; c < 4; ++c)
                xb[c] = __builtin_nontemporal_load(nxt + 16 * c);
        }
        body(x);
    }

    // Merge the 4 group-states across the wave (offsets 16, 32).
    float gm = mw;
    gm = fmaxf(gm, __shfl_xor(gm, 16));
    gm = fmaxf(gm, __shfl_xor(gm, 32));
    const float beta = __expf(mw - gm);
    float L = lw * beta;
    L += __shfl_xor(L, 16);
    L += __shfl_xor(L, 32);
    #pragma unroll
    for (int c = 0; c < 4; ++c) {
        u[c].x *= beta; u[c].y *= beta; u[c].z *= beta; u[c].w *= beta;
        u[c].x += __shfl_xor(u[c].x, 16);
        u[c].y += __shfl_xor(u[c].y, 16);
        u[c].z += __shfl_xor(u[c].z, 16);
        u[c].w += __shfl_xor(u[c].w, 16);
        u[c].x += __shfl_xor(u[c].x, 32);
        u[c].y += __shfl_xor(u[c].y, 32);
        u[c].z += __shfl_xor(u[c].z, 32);
        u[c].w += __shfl_xor(u[c].w, 32);
    }

    const int pi = b * WPB + wi;
    if (lane == 0) { part_m[pi] = gm; part_l[pi] = L; }
    // f4 slot j holds elements [4j, 4j+4): slot = 16c + g, so lane `lane`
    // writes u[lane>>4] to slot `lane` (branchless select avoids scratch).
    f4 val = u[0];
    val = (tg == 1) ? u[1] : val;
    val = (tg == 2) ? u[2] : val;
    val = (tg == 3) ? u[3] : val;
    part_u[(size_t)pi * 64 + lane] = val;
}

// ---------------------------------------------------------------------------
// Kernel 3: combine WPB partials per batch, normalize, apply v_w / v_b.
// out[b,d] = sum_e (u[b,e]/l) * v_w[d,e] + v_b[d]
// Partial-sum over part_u: f4 loads split across 4 row-groups; output
// matmul reads pre-transposed vwt coalesced (unroll 16: 16 loads in flight).
// ---------------------------------------------------------------------------
__global__ __launch_bounds__(256) void k_combine(
    const float* __restrict__ part_m, const float* __restrict__ part_l,
    const f4* __restrict__ part_u, const float* __restrict__ vwt,
    const float* __restrict__ v_b, float* __restrict__ out)
{
    const int b = blockIdx.x, tid = threadIdx.x;
    __shared__ float red[256];
    __shared__ float sf[WPB];
    __shared__ f4 suh[4][64];
    __shared__ __align__(16) float su[DD];

    // Global max over the WPB partial maxima.
    const float pm = (tid < WPB) ? part_m[b * WPB + tid] : -INFINITY;
    red[tid] = pm;
    __syncthreads();
    #pragma unroll
    for (int s = 128; s > 0; s >>= 1) {
        if (tid < s) red[tid] = fmaxf(red[tid], red[tid + s]);
        __syncthreads();
    }
    const float gm = red[0];
    __syncthreads();

    // Rescale factors and global denominator l.
    float lterm = 0.f;
    if (tid < WPB) {
        const float f = __expf(pm - gm);
        sf[tid] = f;
        lterm = part_l[b * WPB + tid] * f;
    }
    red[tid] = lterm;
    __syncthreads();
    #pragma unroll
    for (int s = 128; s > 0; s >>= 1) {
        if (tid < s) red[tid] += red[tid + s];
        __syncthreads();
    }
    const float l = red[0];

    // u[e] = sum_i part_u[b,i,e] * sf[i]  -- f4 slot per thread, 4 row-groups.
    const int slot = tid & 63;      // f4 slot = elements [4*slot, 4*slot+4)
    const int rg   = tid >> 6;      // row-group: rows rg, rg+4, rg+8, ...
    const f4* pu = part_u + (size_t)b * WPB * 64;
    f4 acc = {0.f, 0.f, 0.f, 0.f};
    #pragma unroll 8
    for (int i = rg; i < WPB; i += 4)
        acc += pu[(size_t)i * 64 + slot] * sf[i];
    suh[rg][slot] = acc;
    __syncthreads();
    if (tid < 64) {
        f4 s = suh[0][tid] + suh[1][tid] + suh[2][tid] + suh[3][tid];
        s *= (1.f / l);
        ((f4*)su)[tid] = s;
    }
    __syncthreads();

    // out[b,d] = su . vwt[:,d] + v_b[d]   (thread tid == d, coalesced on vwt)
    float o = v_b[tid];
    #pragma unroll 16
    for (int e = 0; e < DD; ++e) o += su[e] * vwt[e * DD + tid];
    out[b * DD + tid] = o;
}

extern "C" void kernel_launch(void* const* d_in, const int* in_sizes, int n_in,
                              void* d_out, int out_size, void* d_ws, size_t ws_size,
                              hipStream_t stream) {
    const float* query  = (const float*)d_in[0];
    const float* tokens = (const float*)d_in[1];
    const float* q_w    = (const float*)d_in[2];
    const float* q_b    = (const float*)d_in[3];
    const float* k_w    = (const float*)d_in[4];
    // d_in[5] = k_b: softmax-invariant, unused.
    const float* v_w    = (const float*)d_in[6];
    const float* v_b    = (const float*)d_in[7];
    float* out = (float*)d_out;

    // Workspace layout (floats): r[32*256] | part_m[32*64] | part_l[32*64]
    //                            | part_u[32*64*256] | vwt[256*256] (~2.5 MB)
    float* ws     = (float*)d_ws;
    float* r      = ws;
    float* part_m = r + BB * DD;
    float* part_l = part_m + BB * WPB;
    float* part_u = part_l + BB * WPB;      // 48 KiB offset -> float4 aligned
    float* vwt    = part_u + (size_t)BB * WPB * DD;  // 16B-aligned

    k_qr<<<dim3(BB + 8), dim3(256), 0, stream>>>(query, q_w, q_b, k_w,
                                                 v_w, vwt, r);
    k_flash<<<dim3(BLK_PER_B, BB), dim3(256), 0, stream>>>(
        tokens, r, part_m, part_l, (f4*)part_u);
    k_combine<<<dim3(BB), dim3(256), 0, stream>>>(
        part_m, part_l, (const f4*)part_u, vwt, v_b, out);
}